// Round 3
// baseline (1774.070 us; speedup 1.0000x reference)
//
#include <hip/hip_runtime.h>

// Kalman-style linear recurrence, exact chunked-scan parallelization.
//   M = A - L*H ;  x_{k+1} = M x_k + L y_k ;  out_k = H x_k
// CHUNK=64 steps, P=N/64 chunks. Lookback depth 8 with P64 = M^64.
//
// R3: 4-wave blocks (fixes the ~0.8 waves/SIMD residency rocprof showed for
// 64-thread WGs) + 2 chunks per wave (doubles FMA issue per serial-step
// latency window). No __syncthreads: each wave uses its own LDS slice; LDS
// ops within one wave are pipe-ordered, compiler inserts lgkmcnt.

#define CHUNK 64
#define LOOKBACK 8

// ---------------------------------------------------------------- setup ----
__global__ __launch_bounds__(1024) void kf_setup(const float* __restrict__ A,
                                                 const float* __restrict__ Hm,
                                                 const float* __restrict__ Lp,
                                                 float* __restrict__ ws) {
  __shared__ __align__(16) float s0[64 * 68];
  __shared__ __align__(16) float s1[64 * 68];
  const float Lg = Lp[0];
  const int t  = threadIdx.x;      // 0..1023
  const int r  = t >> 4;           // 0..63
  const int c0 = (t & 15) * 4;     // 0,4,..,60

  {
    const float4 a4 = *(const float4*)(A  + r * 64 + c0);
    const float4 h4 = *(const float4*)(Hm + r * 64 + c0);
    float4 m4;
    m4.x = fmaf(-Lg, h4.x, a4.x);
    m4.y = fmaf(-Lg, h4.y, a4.y);
    m4.z = fmaf(-Lg, h4.z, a4.z);
    m4.w = fmaf(-Lg, h4.w, a4.w);
    *(float4*)(s0 + r * 68 + c0) = m4;
  }
  __syncthreads();

  float* src = s0;
  float* dst = s1;
  for (int sq = 0; sq < 6; ++sq) {           // M^2, M^4, ... M^64
    float4 acc = make_float4(0.f, 0.f, 0.f, 0.f);
    const float* srow = src + r * 68;
    #pragma unroll 8
    for (int k = 0; k < 64; ++k) {
      const float  a  = srow[k];
      const float4 b4 = *(const float4*)(src + k * 68 + c0);
      acc.x = fmaf(a, b4.x, acc.x);
      acc.y = fmaf(a, b4.y, acc.y);
      acc.z = fmaf(a, b4.z, acc.z);
      acc.w = fmaf(a, b4.w, acc.w);
    }
    __syncthreads();
    *(float4*)(dst + r * 68 + c0) = acc;
    __syncthreads();
    float* tmp = src; src = dst; dst = tmp;
  }
  *(float4*)(ws + r * 64 + c0) = *(const float4*)(src + r * 68 + c0);
}

// --------------------------------------------------------------- phase 1 ----
// 256-thread blocks = 4 independent waves; each wave runs 2 chunks from x=0.
__global__ __launch_bounds__(256, 3) void kf_phase1(const float* __restrict__ y,
                                                    const float* __restrict__ A,
                                                    const float* __restrict__ Hm,
                                                    const float* __restrict__ Lp,
                                                    float* __restrict__ bvec,
                                                    int Nv, int P) {
  const int lane = threadIdx.x & 63;
  const int w    = threadIdx.x >> 6;
  const int gw   = blockIdx.x * 4 + w;
  const int c0   = gw * 2;
  const int c1   = c0 + 1;
  if (c0 >= P) return;
  const bool has1 = (c1 < P);
  const int  c1e  = has1 ? c1 : c0;

  __shared__ __align__(16) float xs[4][2][64];
  const float Lg = Lp[0];

  float Mrow[64];
  {
    const float* Ar = A  + lane * 64;
    const float* Hr = Hm + lane * 64;
    #pragma unroll
    for (int j = 0; j < 64; j += 4) {
      const float4 a4 = *(const float4*)(Ar + j);
      const float4 h4 = *(const float4*)(Hr + j);
      Mrow[j + 0] = fmaf(-Lg, h4.x, a4.x);
      Mrow[j + 1] = fmaf(-Lg, h4.y, a4.y);
      Mrow[j + 2] = fmaf(-Lg, h4.z, a4.z);
      Mrow[j + 3] = fmaf(-Lg, h4.w, a4.w);
    }
  }

  const float* y0 = y + (size_t)lane * (size_t)Nv + c0  * CHUNK;
  const float* y1 = y + (size_t)lane * (size_t)Nv + c1e * CHUNK;
  float x0 = 0.f, x1 = 0.f;

  #pragma unroll 1
  for (int g = 0; g < 8; ++g) {              // 8 groups x 8 steps
    const float4 a0 = *(const float4*)(y0 + 8 * g + 0);
    const float4 a1 = *(const float4*)(y0 + 8 * g + 4);
    const float4 b0 = *(const float4*)(y1 + 8 * g + 0);
    const float4 b1 = *(const float4*)(y1 + 8 * g + 4);
    float ya[8] = {a0.x, a0.y, a0.z, a0.w, a1.x, a1.y, a1.z, a1.w};
    float yb[8] = {b0.x, b0.y, b0.z, b0.w, b1.x, b1.y, b1.z, b1.w};
    #pragma unroll
    for (int s = 0; s < 8; ++s) {
      xs[w][0][lane] = x0;
      xs[w][1][lane] = x1;
      float p0 = 0.f, p1 = 0.f, q0 = 0.f, q1 = 0.f;
      #pragma unroll
      for (int jj = 0; jj < 16; ++jj) {
        const float4 u = ((const float4*)xs[w][0])[jj];
        const float4 v = ((const float4*)xs[w][1])[jj];
        p0 = fmaf(Mrow[4 * jj + 0], u.x, p0);
        p1 = fmaf(Mrow[4 * jj + 1], u.y, p1);
        q0 = fmaf(Mrow[4 * jj + 0], v.x, q0);
        q1 = fmaf(Mrow[4 * jj + 1], v.y, q1);
        p0 = fmaf(Mrow[4 * jj + 2], u.z, p0);
        p1 = fmaf(Mrow[4 * jj + 3], u.w, p1);
        q0 = fmaf(Mrow[4 * jj + 2], v.z, q0);
        q1 = fmaf(Mrow[4 * jj + 3], v.w, q1);
      }
      x0 = fmaf(Lg, ya[s], p0 + p1);
      x1 = fmaf(Lg, yb[s], q0 + q1);
    }
  }
  bvec[c0 * 64 + lane] = x0;
  if (has1) bvec[c1 * 64 + lane] = x1;
}

// --------------------------------------------------------------- phase 3 ----
// 4 waves/block, 2 chunks/wave. Lookback: s_c0 via depth-D Horner with P64,
// then s_c1 = b[c0] + P64*s_c0 (exact). Replay 64 steps emitting H x_k.
__global__ __launch_bounds__(256, 2) void kf_phase3(const float* __restrict__ y,
                                                    const float* __restrict__ A,
                                                    const float* __restrict__ Hm,
                                                    const float* __restrict__ Lp,
                                                    const float* __restrict__ bvec,
                                                    const float* __restrict__ P64,
                                                    float* __restrict__ out,
                                                    int Nv, int P) {
  const int lane = threadIdx.x & 63;
  const int w    = threadIdx.x >> 6;
  const int gw   = blockIdx.x * 4 + w;
  const int c0   = gw * 2;
  const int c1   = c0 + 1;
  if (c0 >= P) return;
  const bool has1 = (c1 < P);
  const int  c1e  = has1 ? c1 : c0;

  __shared__ __align__(16) float xs[4][2][64];
  const float Lg = Lp[0];

  // ---- lookback (Prow lifetime ends before Mrow/Hrow load) ----
  float x0 = 0.f, x1 = 0.f;
  {
    float Prow[64];
    #pragma unroll
    for (int j = 0; j < 64; j += 4) {
      const float4 p4 = *(const float4*)(P64 + lane * 64 + j);
      Prow[j + 0] = p4.x; Prow[j + 1] = p4.y;
      Prow[j + 2] = p4.z; Prow[j + 3] = p4.w;
    }
    const int D = min(c0, LOOKBACK);
    if (D > 0) {
      x0 = bvec[(c0 - D) * 64 + lane];
      for (int t = D - 1; t >= 1; --t) {
        xs[w][0][lane] = x0;
        float a0 = 0.f, a1 = 0.f;
        #pragma unroll
        for (int jj = 0; jj < 16; ++jj) {
          const float4 u = ((const float4*)xs[w][0])[jj];
          a0 = fmaf(Prow[4 * jj + 0], u.x, a0);
          a1 = fmaf(Prow[4 * jj + 1], u.y, a1);
          a0 = fmaf(Prow[4 * jj + 2], u.z, a0);
          a1 = fmaf(Prow[4 * jj + 3], u.w, a1);
        }
        x0 = a0 + a1 + bvec[(c0 - t) * 64 + lane];
      }
    }
    // s_c1 = b[c0] + P64 * s_c0   (c0==0 -> x0==0 -> x1 = b[0], exact)
    {
      xs[w][0][lane] = x0;
      float a0 = 0.f, a1 = 0.f;
      #pragma unroll
      for (int jj = 0; jj < 16; ++jj) {
        const float4 u = ((const float4*)xs[w][0])[jj];
        a0 = fmaf(Prow[4 * jj + 0], u.x, a0);
        a1 = fmaf(Prow[4 * jj + 1], u.y, a1);
        a0 = fmaf(Prow[4 * jj + 2], u.z, a0);
        a1 = fmaf(Prow[4 * jj + 3], u.w, a1);
      }
      x1 = a0 + a1 + bvec[c0 * 64 + lane];
    }
  }

  float Mrow[64];
  {
    const float* Ar = A  + lane * 64;
    const float* Hr = Hm + lane * 64;
    #pragma unroll
    for (int j = 0; j < 64; j += 4) {
      const float4 a4 = *(const float4*)(Ar + j);
      const float4 h4 = *(const float4*)(Hr + j);
      Mrow[j + 0] = fmaf(-Lg, h4.x, a4.x);
      Mrow[j + 1] = fmaf(-Lg, h4.y, a4.y);
      Mrow[j + 2] = fmaf(-Lg, h4.z, a4.z);
      Mrow[j + 3] = fmaf(-Lg, h4.w, a4.w);
    }
  }
  float Hrow[64];
  #pragma unroll
  for (int j = 0; j < 64; j += 4) {
    const float4 h4 = *(const float4*)(Hm + lane * 64 + j);
    Hrow[j + 0] = h4.x; Hrow[j + 1] = h4.y;
    Hrow[j + 2] = h4.z; Hrow[j + 3] = h4.w;
  }

  const float* y0 = y   + (size_t)lane * (size_t)Nv + c0  * CHUNK;
  const float* y1 = y   + (size_t)lane * (size_t)Nv + c1e * CHUNK;
  float*       o0 = out + (size_t)lane * (size_t)Nv + c0  * CHUNK;
  float*       o1 = out + (size_t)lane * (size_t)Nv + c1e * CHUNK;

  #pragma unroll 1
  for (int g = 0; g < 8; ++g) {              // 8 groups x 8 steps
    const float4 a0 = *(const float4*)(y0 + 8 * g + 0);
    const float4 a1 = *(const float4*)(y0 + 8 * g + 4);
    const float4 b0 = *(const float4*)(y1 + 8 * g + 0);
    const float4 b1 = *(const float4*)(y1 + 8 * g + 4);
    float ya[8] = {a0.x, a0.y, a0.z, a0.w, a1.x, a1.y, a1.z, a1.w};
    float yb[8] = {b0.x, b0.y, b0.z, b0.w, b1.x, b1.y, b1.z, b1.w};
    float oa[8], ob[8];
    #pragma unroll
    for (int s = 0; s < 8; ++s) {
      xs[w][0][lane] = x0;
      xs[w][1][lane] = x1;
      float h0 = 0.f, h1 = 0.f, m0 = 0.f, m1 = 0.f;
      float g0 = 0.f, g1 = 0.f, n0 = 0.f, n1 = 0.f;
      #pragma unroll
      for (int jj = 0; jj < 16; ++jj) {
        const float4 u = ((const float4*)xs[w][0])[jj];
        const float4 v = ((const float4*)xs[w][1])[jj];
        h0 = fmaf(Hrow[4 * jj + 0], u.x, h0);
        h1 = fmaf(Hrow[4 * jj + 1], u.y, h1);
        m0 = fmaf(Mrow[4 * jj + 0], u.x, m0);
        m1 = fmaf(Mrow[4 * jj + 1], u.y, m1);
        g0 = fmaf(Hrow[4 * jj + 0], v.x, g0);
        g1 = fmaf(Hrow[4 * jj + 1], v.y, g1);
        n0 = fmaf(Mrow[4 * jj + 0], v.x, n0);
        n1 = fmaf(Mrow[4 * jj + 1], v.y, n1);
        h0 = fmaf(Hrow[4 * jj + 2], u.z, h0);
        h1 = fmaf(Hrow[4 * jj + 3], u.w, h1);
        m0 = fmaf(Mrow[4 * jj + 2], u.z, m0);
        m1 = fmaf(Mrow[4 * jj + 3], u.w, m1);
        g0 = fmaf(Hrow[4 * jj + 2], v.z, g0);
        g1 = fmaf(Hrow[4 * jj + 3], v.w, g1);
        n0 = fmaf(Mrow[4 * jj + 2], v.z, n0);
        n1 = fmaf(Mrow[4 * jj + 3], v.w, n1);
      }
      oa[s] = h0 + h1;
      ob[s] = g0 + g1;
      x0 = fmaf(Lg, ya[s], m0 + m1);
      x1 = fmaf(Lg, yb[s], n0 + n1);
    }
    *(float4*)(o0 + 8 * g + 0) = make_float4(oa[0], oa[1], oa[2], oa[3]);
    *(float4*)(o0 + 8 * g + 4) = make_float4(oa[4], oa[5], oa[6], oa[7]);
    if (has1) {
      *(float4*)(o1 + 8 * g + 0) = make_float4(ob[0], ob[1], ob[2], ob[3]);
      *(float4*)(o1 + 8 * g + 4) = make_float4(ob[4], ob[5], ob[6], ob[7]);
    }
  }
}

// ---------------------------------------------------------------------------
extern "C" void kernel_launch(void* const* d_in, const int* in_sizes, int n_in,
                              void* d_out, int out_size, void* d_ws, size_t ws_size,
                              hipStream_t stream) {
  const float* y  = (const float*)d_in[0];
  const float* A  = (const float*)d_in[1];
  const float* Hm = (const float*)d_in[2];
  const float* Lp = (const float*)d_in[3];
  const int Nv = in_sizes[0] / 64;          // 200000 (multiple of 64)
  const int P  = Nv / CHUNK;                // 3125

  float* ws   = (float*)d_ws;
  float* P64  = ws;            // 4096 floats
  float* bvec = ws + 4096;     // P*64 floats (~800 KB)

  const int nwaves = (P + 1) / 2;           // 2 chunks per wave
  const int blocks = (nwaves + 3) / 4;      // 4 waves per block

  kf_setup<<<1, 1024, 0, stream>>>(A, Hm, Lp, P64);
  kf_phase1<<<blocks, 256, 0, stream>>>(y, A, Hm, Lp, bvec, Nv, P);
  kf_phase3<<<blocks, 256, 0, stream>>>(y, A, Hm, Lp, bvec, P64, (float*)d_out, Nv, P);
}

// Round 4
// 965.561 us; speedup vs baseline: 1.8373x; 1.8373x over previous
//
#include <hip/hip_runtime.h>

// Kalman-style linear recurrence, exact chunked-scan parallelization.
//   M = A - L*H ;  x_{k+1} = M x_k + L y_k ;  out_k = H x_k
// CHUNK=64 steps, P=N/64 chunks. Lookback depth 8 with P64 = M^64.
//
// R4: identical structure to R3 (4-wave blocks, 2 chunks/wave, no barriers)
// but __launch_bounds__(256, 1). Empirical allocator behavior on this TU:
//   (64,1) -> 232 VGPR no spill ; (64,2),(256,2),(256,3) -> 128 VGPR + massive
//   scratch spill (R3: FETCH 2.05 GB, VALU 3.5%). min_waves=1 sets the full
//   512-reg budget and disables the occupancy-chasing heuristic.

#define CHUNK 64
#define LOOKBACK 8

// ---------------------------------------------------------------- setup ----
__global__ __launch_bounds__(1024) void kf_setup(const float* __restrict__ A,
                                                 const float* __restrict__ Hm,
                                                 const float* __restrict__ Lp,
                                                 float* __restrict__ ws) {
  __shared__ __align__(16) float s0[64 * 68];
  __shared__ __align__(16) float s1[64 * 68];
  const float Lg = Lp[0];
  const int t  = threadIdx.x;      // 0..1023
  const int r  = t >> 4;           // 0..63
  const int c0 = (t & 15) * 4;     // 0,4,..,60

  {
    const float4 a4 = *(const float4*)(A  + r * 64 + c0);
    const float4 h4 = *(const float4*)(Hm + r * 64 + c0);
    float4 m4;
    m4.x = fmaf(-Lg, h4.x, a4.x);
    m4.y = fmaf(-Lg, h4.y, a4.y);
    m4.z = fmaf(-Lg, h4.z, a4.z);
    m4.w = fmaf(-Lg, h4.w, a4.w);
    *(float4*)(s0 + r * 68 + c0) = m4;
  }
  __syncthreads();

  float* src = s0;
  float* dst = s1;
  for (int sq = 0; sq < 6; ++sq) {           // M^2, M^4, ... M^64
    float4 acc = make_float4(0.f, 0.f, 0.f, 0.f);
    const float* srow = src + r * 68;
    #pragma unroll 8
    for (int k = 0; k < 64; ++k) {
      const float  a  = srow[k];
      const float4 b4 = *(const float4*)(src + k * 68 + c0);
      acc.x = fmaf(a, b4.x, acc.x);
      acc.y = fmaf(a, b4.y, acc.y);
      acc.z = fmaf(a, b4.z, acc.z);
      acc.w = fmaf(a, b4.w, acc.w);
    }
    __syncthreads();
    *(float4*)(dst + r * 68 + c0) = acc;
    __syncthreads();
    float* tmp = src; src = dst; dst = tmp;
  }
  *(float4*)(ws + r * 64 + c0) = *(const float4*)(src + r * 68 + c0);
}

// --------------------------------------------------------------- phase 1 ----
// 256-thread blocks = 4 independent waves; each wave runs 2 chunks from x=0.
__global__ __launch_bounds__(256, 1) void kf_phase1(const float* __restrict__ y,
                                                    const float* __restrict__ A,
                                                    const float* __restrict__ Hm,
                                                    const float* __restrict__ Lp,
                                                    float* __restrict__ bvec,
                                                    int Nv, int P) {
  const int lane = threadIdx.x & 63;
  const int w    = threadIdx.x >> 6;
  const int gw   = blockIdx.x * 4 + w;
  const int c0   = gw * 2;
  const int c1   = c0 + 1;
  if (c0 >= P) return;
  const bool has1 = (c1 < P);
  const int  c1e  = has1 ? c1 : c0;

  __shared__ __align__(16) float xs[4][2][64];
  const float Lg = Lp[0];

  float Mrow[64];
  {
    const float* Ar = A  + lane * 64;
    const float* Hr = Hm + lane * 64;
    #pragma unroll
    for (int j = 0; j < 64; j += 4) {
      const float4 a4 = *(const float4*)(Ar + j);
      const float4 h4 = *(const float4*)(Hr + j);
      Mrow[j + 0] = fmaf(-Lg, h4.x, a4.x);
      Mrow[j + 1] = fmaf(-Lg, h4.y, a4.y);
      Mrow[j + 2] = fmaf(-Lg, h4.z, a4.z);
      Mrow[j + 3] = fmaf(-Lg, h4.w, a4.w);
    }
  }

  const float* y0 = y + (size_t)lane * (size_t)Nv + c0  * CHUNK;
  const float* y1 = y + (size_t)lane * (size_t)Nv + c1e * CHUNK;
  float x0 = 0.f, x1 = 0.f;

  #pragma unroll 1
  for (int g = 0; g < 8; ++g) {              // 8 groups x 8 steps
    const float4 a0 = *(const float4*)(y0 + 8 * g + 0);
    const float4 a1 = *(const float4*)(y0 + 8 * g + 4);
    const float4 b0 = *(const float4*)(y1 + 8 * g + 0);
    const float4 b1 = *(const float4*)(y1 + 8 * g + 4);
    float ya[8] = {a0.x, a0.y, a0.z, a0.w, a1.x, a1.y, a1.z, a1.w};
    float yb[8] = {b0.x, b0.y, b0.z, b0.w, b1.x, b1.y, b1.z, b1.w};
    #pragma unroll
    for (int s = 0; s < 8; ++s) {
      xs[w][0][lane] = x0;
      xs[w][1][lane] = x1;
      float p0 = 0.f, p1 = 0.f, q0 = 0.f, q1 = 0.f;
      #pragma unroll
      for (int jj = 0; jj < 16; ++jj) {
        const float4 u = ((const float4*)xs[w][0])[jj];
        const float4 v = ((const float4*)xs[w][1])[jj];
        p0 = fmaf(Mrow[4 * jj + 0], u.x, p0);
        p1 = fmaf(Mrow[4 * jj + 1], u.y, p1);
        q0 = fmaf(Mrow[4 * jj + 0], v.x, q0);
        q1 = fmaf(Mrow[4 * jj + 1], v.y, q1);
        p0 = fmaf(Mrow[4 * jj + 2], u.z, p0);
        p1 = fmaf(Mrow[4 * jj + 3], u.w, p1);
        q0 = fmaf(Mrow[4 * jj + 2], v.z, q0);
        q1 = fmaf(Mrow[4 * jj + 3], v.w, q1);
      }
      x0 = fmaf(Lg, ya[s], p0 + p1);
      x1 = fmaf(Lg, yb[s], q0 + q1);
    }
  }
  bvec[c0 * 64 + lane] = x0;
  if (has1) bvec[c1 * 64 + lane] = x1;
}

// --------------------------------------------------------------- phase 3 ----
// 4 waves/block, 2 chunks/wave. Lookback: s_c0 via depth-D Horner with P64,
// then s_c1 = b[c0] + P64*s_c0 (exact). Replay 64 steps emitting H x_k.
__global__ __launch_bounds__(256, 1) void kf_phase3(const float* __restrict__ y,
                                                    const float* __restrict__ A,
                                                    const float* __restrict__ Hm,
                                                    const float* __restrict__ Lp,
                                                    const float* __restrict__ bvec,
                                                    const float* __restrict__ P64,
                                                    float* __restrict__ out,
                                                    int Nv, int P) {
  const int lane = threadIdx.x & 63;
  const int w    = threadIdx.x >> 6;
  const int gw   = blockIdx.x * 4 + w;
  const int c0   = gw * 2;
  const int c1   = c0 + 1;
  if (c0 >= P) return;
  const bool has1 = (c1 < P);
  const int  c1e  = has1 ? c1 : c0;

  __shared__ __align__(16) float xs[4][2][64];
  const float Lg = Lp[0];

  // ---- lookback (Prow lifetime ends before Mrow/Hrow load) ----
  float x0 = 0.f, x1 = 0.f;
  {
    float Prow[64];
    #pragma unroll
    for (int j = 0; j < 64; j += 4) {
      const float4 p4 = *(const float4*)(P64 + lane * 64 + j);
      Prow[j + 0] = p4.x; Prow[j + 1] = p4.y;
      Prow[j + 2] = p4.z; Prow[j + 3] = p4.w;
    }
    const int D = min(c0, LOOKBACK);
    if (D > 0) {
      x0 = bvec[(c0 - D) * 64 + lane];
      for (int t = D - 1; t >= 1; --t) {
        xs[w][0][lane] = x0;
        float a0 = 0.f, a1 = 0.f;
        #pragma unroll
        for (int jj = 0; jj < 16; ++jj) {
          const float4 u = ((const float4*)xs[w][0])[jj];
          a0 = fmaf(Prow[4 * jj + 0], u.x, a0);
          a1 = fmaf(Prow[4 * jj + 1], u.y, a1);
          a0 = fmaf(Prow[4 * jj + 2], u.z, a0);
          a1 = fmaf(Prow[4 * jj + 3], u.w, a1);
        }
        x0 = a0 + a1 + bvec[(c0 - t) * 64 + lane];
      }
    }
    // s_c1 = b[c0] + P64 * s_c0   (c0==0 -> x0==0 -> x1 = b[0], exact)
    {
      xs[w][0][lane] = x0;
      float a0 = 0.f, a1 = 0.f;
      #pragma unroll
      for (int jj = 0; jj < 16; ++jj) {
        const float4 u = ((const float4*)xs[w][0])[jj];
        a0 = fmaf(Prow[4 * jj + 0], u.x, a0);
        a1 = fmaf(Prow[4 * jj + 1], u.y, a1);
        a0 = fmaf(Prow[4 * jj + 2], u.z, a0);
        a1 = fmaf(Prow[4 * jj + 3], u.w, a1);
      }
      x1 = a0 + a1 + bvec[c0 * 64 + lane];
    }
  }

  float Mrow[64];
  {
    const float* Ar = A  + lane * 64;
    const float* Hr = Hm + lane * 64;
    #pragma unroll
    for (int j = 0; j < 64; j += 4) {
      const float4 a4 = *(const float4*)(Ar + j);
      const float4 h4 = *(const float4*)(Hr + j);
      Mrow[j + 0] = fmaf(-Lg, h4.x, a4.x);
      Mrow[j + 1] = fmaf(-Lg, h4.y, a4.y);
      Mrow[j + 2] = fmaf(-Lg, h4.z, a4.z);
      Mrow[j + 3] = fmaf(-Lg, h4.w, a4.w);
    }
  }
  float Hrow[64];
  #pragma unroll
  for (int j = 0; j < 64; j += 4) {
    const float4 h4 = *(const float4*)(Hm + lane * 64 + j);
    Hrow[j + 0] = h4.x; Hrow[j + 1] = h4.y;
    Hrow[j + 2] = h4.z; Hrow[j + 3] = h4.w;
  }

  const float* y0 = y   + (size_t)lane * (size_t)Nv + c0  * CHUNK;
  const float* y1 = y   + (size_t)lane * (size_t)Nv + c1e * CHUNK;
  float*       o0 = out + (size_t)lane * (size_t)Nv + c0  * CHUNK;
  float*       o1 = out + (size_t)lane * (size_t)Nv + c1e * CHUNK;

  #pragma unroll 1
  for (int g = 0; g < 8; ++g) {              // 8 groups x 8 steps
    const float4 a0 = *(const float4*)(y0 + 8 * g + 0);
    const float4 a1 = *(const float4*)(y0 + 8 * g + 4);
    const float4 b0 = *(const float4*)(y1 + 8 * g + 0);
    const float4 b1 = *(const float4*)(y1 + 8 * g + 4);
    float ya[8] = {a0.x, a0.y, a0.z, a0.w, a1.x, a1.y, a1.z, a1.w};
    float yb[8] = {b0.x, b0.y, b0.z, b0.w, b1.x, b1.y, b1.z, b1.w};
    float oa[8], ob[8];
    #pragma unroll
    for (int s = 0; s < 8; ++s) {
      xs[w][0][lane] = x0;
      xs[w][1][lane] = x1;
      float h0 = 0.f, h1 = 0.f, m0 = 0.f, m1 = 0.f;
      float g0 = 0.f, g1 = 0.f, n0 = 0.f, n1 = 0.f;
      #pragma unroll
      for (int jj = 0; jj < 16; ++jj) {
        const float4 u = ((const float4*)xs[w][0])[jj];
        const float4 v = ((const float4*)xs[w][1])[jj];
        h0 = fmaf(Hrow[4 * jj + 0], u.x, h0);
        h1 = fmaf(Hrow[4 * jj + 1], u.y, h1);
        m0 = fmaf(Mrow[4 * jj + 0], u.x, m0);
        m1 = fmaf(Mrow[4 * jj + 1], u.y, m1);
        g0 = fmaf(Hrow[4 * jj + 0], v.x, g0);
        g1 = fmaf(Hrow[4 * jj + 1], v.y, g1);
        n0 = fmaf(Mrow[4 * jj + 0], v.x, n0);
        n1 = fmaf(Mrow[4 * jj + 1], v.y, n1);
        h0 = fmaf(Hrow[4 * jj + 2], u.z, h0);
        h1 = fmaf(Hrow[4 * jj + 3], u.w, h1);
        m0 = fmaf(Mrow[4 * jj + 2], u.z, m0);
        m1 = fmaf(Mrow[4 * jj + 3], u.w, m1);
        g0 = fmaf(Hrow[4 * jj + 2], v.z, g0);
        g1 = fmaf(Hrow[4 * jj + 3], v.w, g1);
        n0 = fmaf(Mrow[4 * jj + 2], v.z, n0);
        n1 = fmaf(Mrow[4 * jj + 3], v.w, n1);
      }
      oa[s] = h0 + h1;
      ob[s] = g0 + g1;
      x0 = fmaf(Lg, ya[s], m0 + m1);
      x1 = fmaf(Lg, yb[s], n0 + n1);
    }
    *(float4*)(o0 + 8 * g + 0) = make_float4(oa[0], oa[1], oa[2], oa[3]);
    *(float4*)(o0 + 8 * g + 4) = make_float4(oa[4], oa[5], oa[6], oa[7]);
    if (has1) {
      *(float4*)(o1 + 8 * g + 0) = make_float4(ob[0], ob[1], ob[2], ob[3]);
      *(float4*)(o1 + 8 * g + 4) = make_float4(ob[4], ob[5], ob[6], ob[7]);
    }
  }
}

// ---------------------------------------------------------------------------
extern "C" void kernel_launch(void* const* d_in, const int* in_sizes, int n_in,
                              void* d_out, int out_size, void* d_ws, size_t ws_size,
                              hipStream_t stream) {
  const float* y  = (const float*)d_in[0];
  const float* A  = (const float*)d_in[1];
  const float* Hm = (const float*)d_in[2];
  const float* Lp = (const float*)d_in[3];
  const int Nv = in_sizes[0] / 64;          // 200000 (multiple of 64)
  const int P  = Nv / CHUNK;                // 3125

  float* ws   = (float*)d_ws;
  float* P64  = ws;            // 4096 floats
  float* bvec = ws + 4096;     // P*64 floats (~800 KB)

  const int nwaves = (P + 1) / 2;           // 2 chunks per wave
  const int blocks = (nwaves + 3) / 4;      // 4 waves per block

  kf_setup<<<1, 1024, 0, stream>>>(A, Hm, Lp, P64);
  kf_phase1<<<blocks, 256, 0, stream>>>(y, A, Hm, Lp, bvec, Nv, P);
  kf_phase3<<<blocks, 256, 0, stream>>>(y, A, Hm, Lp, bvec, P64, (float*)d_out, Nv, P);
}

// Round 5
// 342.531 us; speedup vs baseline: 5.1793x; 2.8189x over previous
//
#include <hip/hip_runtime.h>

// Kalman-style linear recurrence, exact chunked-scan parallelization.
//   M = A - L*H ;  x_{k+1} = M x_k + L y_k ;  out_k = H x_k
// CHUNK=64 steps, P=N/64 chunks. Lookback depth 8 with P64 = M^64.
//
// R5: phase kernels = R2's proven single-chunk-per-wave register layout
// (232 VGPR, no spill) x R3's residency fix (4 waves per 256-thread block,
// private LDS slice per wave, no barriers). Lesson bank:
//   - min_waves>1 launch bounds -> 128-reg cap + catastrophic scratch spill
//   - >~250 live regs -> spill regardless (256 = architected VGPR cap;
//     512 is VGPR+AGPR unified and unusable for plain spills)  [R4]
//   - 64-thread workgroups -> ~0.8 waves/SIMD resident             [R2]

#define CHUNK 64
#define LOOKBACK 8

// ---------------------------------------------------------------- setup ----
__global__ __launch_bounds__(1024) void kf_setup(const float* __restrict__ A,
                                                 const float* __restrict__ Hm,
                                                 const float* __restrict__ Lp,
                                                 float* __restrict__ ws) {
  __shared__ __align__(16) float s0[64 * 68];
  __shared__ __align__(16) float s1[64 * 68];
  const float Lg = Lp[0];
  const int t  = threadIdx.x;      // 0..1023
  const int r  = t >> 4;           // 0..63
  const int c0 = (t & 15) * 4;     // 0,4,..,60

  {
    const float4 a4 = *(const float4*)(A  + r * 64 + c0);
    const float4 h4 = *(const float4*)(Hm + r * 64 + c0);
    float4 m4;
    m4.x = fmaf(-Lg, h4.x, a4.x);
    m4.y = fmaf(-Lg, h4.y, a4.y);
    m4.z = fmaf(-Lg, h4.z, a4.z);
    m4.w = fmaf(-Lg, h4.w, a4.w);
    *(float4*)(s0 + r * 68 + c0) = m4;
  }
  __syncthreads();

  float* src = s0;
  float* dst = s1;
  for (int sq = 0; sq < 6; ++sq) {           // M^2, M^4, ... M^64
    float4 acc = make_float4(0.f, 0.f, 0.f, 0.f);
    const float* srow = src + r * 68;
    #pragma unroll 8
    for (int k = 0; k < 64; ++k) {
      const float  a  = srow[k];
      const float4 b4 = *(const float4*)(src + k * 68 + c0);
      acc.x = fmaf(a, b4.x, acc.x);
      acc.y = fmaf(a, b4.y, acc.y);
      acc.z = fmaf(a, b4.z, acc.z);
      acc.w = fmaf(a, b4.w, acc.w);
    }
    __syncthreads();
    *(float4*)(dst + r * 68 + c0) = acc;
    __syncthreads();
    float* tmp = src; src = dst; dst = tmp;
  }
  *(float4*)(ws + r * 64 + c0) = *(const float4*)(src + r * 68 + c0);
}

// --------------------------------------------------------------- phase 1 ----
// 4 waves/block, 1 chunk/wave: run 64 steps from x=0, store final state.
__global__ __launch_bounds__(256, 1) void kf_phase1(const float* __restrict__ y,
                                                    const float* __restrict__ A,
                                                    const float* __restrict__ Hm,
                                                    const float* __restrict__ Lp,
                                                    float* __restrict__ bvec,
                                                    int Nv, int P) {
  const int lane = threadIdx.x & 63;
  const int w    = threadIdx.x >> 6;
  const int c    = blockIdx.x * 4 + w;
  if (c >= P) return;

  __shared__ __align__(16) float xs[4][64];
  const float Lg = Lp[0];

  float Mrow[64];
  {
    const float* Ar = A  + lane * 64;
    const float* Hr = Hm + lane * 64;
    #pragma unroll
    for (int j = 0; j < 64; j += 4) {
      const float4 a4 = *(const float4*)(Ar + j);
      const float4 h4 = *(const float4*)(Hr + j);
      Mrow[j + 0] = fmaf(-Lg, h4.x, a4.x);
      Mrow[j + 1] = fmaf(-Lg, h4.y, a4.y);
      Mrow[j + 2] = fmaf(-Lg, h4.z, a4.z);
      Mrow[j + 3] = fmaf(-Lg, h4.w, a4.w);
    }
  }

  const float* yrow = y + (size_t)lane * (size_t)Nv + c * CHUNK;
  float x = 0.f;

  #pragma unroll 1
  for (int t = 0; t < 4; ++t) {
    const float4 y0 = *(const float4*)(yrow + 16 * t + 0);
    const float4 y1 = *(const float4*)(yrow + 16 * t + 4);
    const float4 y2 = *(const float4*)(yrow + 16 * t + 8);
    const float4 y3 = *(const float4*)(yrow + 16 * t + 12);
    float yb[16];
    yb[0] = y0.x; yb[1] = y0.y; yb[2]  = y0.z; yb[3]  = y0.w;
    yb[4] = y1.x; yb[5] = y1.y; yb[6]  = y1.z; yb[7]  = y1.w;
    yb[8] = y2.x; yb[9] = y2.y; yb[10] = y2.z; yb[11] = y2.w;
    yb[12] = y3.x; yb[13] = y3.y; yb[14] = y3.z; yb[15] = y3.w;
    #pragma unroll
    for (int kk = 0; kk < 16; ++kk) {
      xs[w][lane] = x;
      float a0 = 0.f, a1 = 0.f;
      #pragma unroll
      for (int jj = 0; jj < 16; ++jj) {
        const float4 xv = ((const float4*)xs[w])[jj];
        a0 = fmaf(Mrow[4 * jj + 0], xv.x, a0);
        a1 = fmaf(Mrow[4 * jj + 1], xv.y, a1);
        a0 = fmaf(Mrow[4 * jj + 2], xv.z, a0);
        a1 = fmaf(Mrow[4 * jj + 3], xv.w, a1);
      }
      x = fmaf(Lg, yb[kk], a0 + a1);
    }
  }
  bvec[c * 64 + lane] = x;
}

// --------------------------------------------------------------- phase 3 ----
// 4 waves/block, 1 chunk/wave. Depth-D Horner lookback with P64, then replay
// 64 steps emitting out_k = H x_k.
__global__ __launch_bounds__(256, 1) void kf_phase3(const float* __restrict__ y,
                                                    const float* __restrict__ A,
                                                    const float* __restrict__ Hm,
                                                    const float* __restrict__ Lp,
                                                    const float* __restrict__ bvec,
                                                    const float* __restrict__ P64,
                                                    float* __restrict__ out,
                                                    int Nv, int P) {
  const int lane = threadIdx.x & 63;
  const int w    = threadIdx.x >> 6;
  const int c    = blockIdx.x * 4 + w;
  if (c >= P) return;

  __shared__ __align__(16) float xs[4][64];
  const float Lg = Lp[0];

  // ---- lookback: s_c = b[c-1] + P64*(b[c-2] + P64*(... b[c-D]))
  float x = 0.f;
  {
    const int D = min(c, LOOKBACK);
    if (D > 0) {
      float Prow[64];   // lifetime ends before Mrow/Hrow load
      #pragma unroll
      for (int j = 0; j < 64; j += 4) {
        const float4 p4 = *(const float4*)(P64 + lane * 64 + j);
        Prow[j + 0] = p4.x; Prow[j + 1] = p4.y;
        Prow[j + 2] = p4.z; Prow[j + 3] = p4.w;
      }
      x = bvec[(c - D) * 64 + lane];
      for (int t = D - 1; t >= 1; --t) {
        xs[w][lane] = x;
        float a0 = 0.f, a1 = 0.f;
        #pragma unroll
        for (int jj = 0; jj < 16; ++jj) {
          const float4 u = ((const float4*)xs[w])[jj];
          a0 = fmaf(Prow[4 * jj + 0], u.x, a0);
          a1 = fmaf(Prow[4 * jj + 1], u.y, a1);
          a0 = fmaf(Prow[4 * jj + 2], u.z, a0);
          a1 = fmaf(Prow[4 * jj + 3], u.w, a1);
        }
        x = a0 + a1 + bvec[(c - t) * 64 + lane];
      }
    }
  }

  float Mrow[64];
  {
    const float* Ar = A  + lane * 64;
    const float* Hr = Hm + lane * 64;
    #pragma unroll
    for (int j = 0; j < 64; j += 4) {
      const float4 a4 = *(const float4*)(Ar + j);
      const float4 h4 = *(const float4*)(Hr + j);
      Mrow[j + 0] = fmaf(-Lg, h4.x, a4.x);
      Mrow[j + 1] = fmaf(-Lg, h4.y, a4.y);
      Mrow[j + 2] = fmaf(-Lg, h4.z, a4.z);
      Mrow[j + 3] = fmaf(-Lg, h4.w, a4.w);
    }
  }
  float Hrow[64];
  #pragma unroll
  for (int j = 0; j < 64; j += 4) {
    const float4 h4 = *(const float4*)(Hm + lane * 64 + j);
    Hrow[j + 0] = h4.x; Hrow[j + 1] = h4.y;
    Hrow[j + 2] = h4.z; Hrow[j + 3] = h4.w;
  }

  const float* yrow = y   + (size_t)lane * (size_t)Nv + c * CHUNK;
  float*       orow = out + (size_t)lane * (size_t)Nv + c * CHUNK;

  #pragma unroll 1
  for (int t = 0; t < 4; ++t) {
    const float4 y0 = *(const float4*)(yrow + 16 * t + 0);
    const float4 y1 = *(const float4*)(yrow + 16 * t + 4);
    const float4 y2 = *(const float4*)(yrow + 16 * t + 8);
    const float4 y3 = *(const float4*)(yrow + 16 * t + 12);
    float yb[16];
    yb[0] = y0.x; yb[1] = y0.y; yb[2]  = y0.z; yb[3]  = y0.w;
    yb[4] = y1.x; yb[5] = y1.y; yb[6]  = y1.z; yb[7]  = y1.w;
    yb[8] = y2.x; yb[9] = y2.y; yb[10] = y2.z; yb[11] = y2.w;
    yb[12] = y3.x; yb[13] = y3.y; yb[14] = y3.z; yb[15] = y3.w;

    float ob[16];                    // 16 outputs -> 64 B contiguous store
    #pragma unroll
    for (int kk = 0; kk < 16; ++kk) {
      xs[w][lane] = x;
      float h0 = 0.f, h1 = 0.f, m0 = 0.f, m1 = 0.f;
      #pragma unroll
      for (int jj = 0; jj < 16; ++jj) {
        const float4 xv = ((const float4*)xs[w])[jj];
        h0 = fmaf(Hrow[4 * jj + 0], xv.x, h0);
        h1 = fmaf(Hrow[4 * jj + 1], xv.y, h1);
        m0 = fmaf(Mrow[4 * jj + 0], xv.x, m0);
        m1 = fmaf(Mrow[4 * jj + 1], xv.y, m1);
        h0 = fmaf(Hrow[4 * jj + 2], xv.z, h0);
        h1 = fmaf(Hrow[4 * jj + 3], xv.w, h1);
        m0 = fmaf(Mrow[4 * jj + 2], xv.z, m0);
        m1 = fmaf(Mrow[4 * jj + 3], xv.w, m1);
      }
      ob[kk] = h0 + h1;
      x = fmaf(Lg, yb[kk], m0 + m1);
    }
    *(float4*)(orow + 16 * t + 0)  = make_float4(ob[0],  ob[1],  ob[2],  ob[3]);
    *(float4*)(orow + 16 * t + 4)  = make_float4(ob[4],  ob[5],  ob[6],  ob[7]);
    *(float4*)(orow + 16 * t + 8)  = make_float4(ob[8],  ob[9],  ob[10], ob[11]);
    *(float4*)(orow + 16 * t + 12) = make_float4(ob[12], ob[13], ob[14], ob[15]);
  }
}

// ---------------------------------------------------------------------------
extern "C" void kernel_launch(void* const* d_in, const int* in_sizes, int n_in,
                              void* d_out, int out_size, void* d_ws, size_t ws_size,
                              hipStream_t stream) {
  const float* y  = (const float*)d_in[0];
  const float* A  = (const float*)d_in[1];
  const float* Hm = (const float*)d_in[2];
  const float* Lp = (const float*)d_in[3];
  const int Nv = in_sizes[0] / 64;          // 200000 (multiple of 64)
  const int P  = Nv / CHUNK;                // 3125

  float* ws   = (float*)d_ws;
  float* P64  = ws;            // 4096 floats
  float* bvec = ws + 4096;     // P*64 floats (~800 KB)

  const int blocks = (P + 3) / 4;           // 4 waves (chunks) per block

  kf_setup<<<1, 1024, 0, stream>>>(A, Hm, Lp, P64);
  kf_phase1<<<blocks, 256, 0, stream>>>(y, A, Hm, Lp, bvec, Nv, P);
  kf_phase3<<<blocks, 256, 0, stream>>>(y, A, Hm, Lp, bvec, P64, (float*)d_out, Nv, P);
}